// Round 1
// baseline (226.355 us; speedup 1.0000x reference)
//
#include <hip/hip_runtime.h>
#include <math.h>

#define T_DIM 16384
#define A_DIM 128
#define K_DIM 128
#define N_STEPS 16
#define E_DIM 126
#define NSEQ 4

// step0: 16-atom x 256-t tiles -> 8 atiles x 64 ttiles = 512 tiles/seq
#define NPT0 512
// inc: 8-atom tiles, 16 atiles x 2 halves x 2 parities = 64 compute blocks/seq
#define NAT8 16
#define TT 256
#define NTT 64
#define HB 8192
#define RL_LEN 8319     // [base-64, base+8255]
#define SS_LEN 383
#define SPAD 16         // mailbox stride: 16 u64 = 128 B (one line per slot)

#define PIDX(i) ((i) + ((i) >> 5))   // +1 pad per 32 dwords: conflict-free

#define NB_STEP0 (NPT0 * NSEQ)       // 2048
#define NB_INC   (65 * NSEQ)         // 260
#define NB_TOTAL (NB_STEP0 + NB_INC + 1)

#define SM_U64 4960                  // 39680 B shared arena (union of roles)

// order-preserving pack: bigger u64 == (bigger value, then smaller flat idx).
__device__ inline unsigned long long pack_vi(float v, int fi) {
    unsigned int b = __float_as_uint(v);
    b = (b & 0x80000000u) ? ~b : (b | 0x80000000u);
    return ((unsigned long long)b << 32) | (unsigned int)(~fi);
}
__device__ inline void unpack_vi(unsigned long long p, float* v, int* fi) {
    unsigned int lo = (unsigned int)(p & 0xffffffffu);
    unsigned int b = (unsigned int)(p >> 32);
    unsigned int fb = (b & 0x80000000u) ? (b & 0x7fffffffu) : ~b;
    *v = __uint_as_float(fb);
    *fi = (int)(~lo);
}
__device__ inline unsigned long long u64max(unsigned long long a, unsigned long long b) {
    return a > b ? a : b;
}
__device__ inline unsigned long long pollu64(const unsigned long long* p) {
    unsigned long long v = __hip_atomic_load(p, __ATOMIC_RELAXED,
                                             __HIP_MEMORY_SCOPE_AGENT);
    while (v == 0ULL) {
        __builtin_amdgcn_s_sleep(1);
        v = __hip_atomic_load(p, __ATOMIC_RELAXED, __HIP_MEMORY_SCOPE_AGENT);
    }
    return v;
}
__device__ inline void pollcnt(const int* p, int target) {
    int v = __hip_atomic_load(p, __ATOMIC_RELAXED, __HIP_MEMORY_SCOPE_AGENT);
    while (v < target) {
        __builtin_amdgcn_s_sleep(1);
        v = __hip_atomic_load(p, __ATOMIC_RELAXED, __HIP_MEMORY_SCOPE_AGENT);
    }
}

// ---------------------------------------------------------------------------
// arena u64 layout: pmax[0,2048) | dslots[2048,32768) (15*4*32 slots * SPAD)
// | wslot[32768,33728) (unused) | w0slot[33728,33792) (4*SPAD, emb0 path only)
// | ctrl ints at +33792: cnt[seq*32], done at [128], norm2 floats at [160+seq*32]
__global__ __launch_bounds__(256) void k_prep(
    const float* __restrict__ d, float* __restrict__ du,
    unsigned long long* __restrict__ arena) {
    int blk = blockIdx.x, tid = threadIdx.x;
    if (blk < 128) {
        __shared__ float s[128];
        float v = 0.0f;
        if (tid < 128) { v = d[blk * K_DIM + tid]; s[tid] = v * v; }
        __syncthreads();
        for (int off = 64; off > 0; off >>= 1) {
            if (tid < off) s[tid] += s[tid + off];
            __syncthreads();
        }
        if (tid < 128) du[blk * K_DIM + tid] = v / (sqrtf(s[0]) + 1e-8f);
    } else {
        int zb = blk - 128;                       // 0..63
        for (int i = zb * 256 + tid; i < 31744; i += 64 * 256)
            arena[2048 + i] = 0ULL;
        if (blk == 128) {
            int* ctrl = (int*)(arena + 33792);
            if (tid < NSEQ) {
                ctrl[tid * 32] = 0;                         // cnt
                ((float*)ctrl)[160 + tid * 32] = 0.0f;      // norm2
            }
            if (tid == 4) ctrl[128] = 0;                    // done
        }
    }
}

// ---------------------------------------------------------------------------
// 16a x 256t engine (R10/R11-proven bit-exact): du via wave-uniform s_load
// float4 (4 atoms/wave); res via padded b32 sliding window. k ascending.
__device__ inline unsigned long long tile16(
    const float* __restrict__ duP, const float* __restrict__ rsh,
    int L0, int a_lo, int t_lo, int tid, unsigned long long* red4) {
    float acc[4][4];
    #pragma unroll
    for (int i = 0; i < 4; i++)
        #pragma unroll
        for (int j = 0; j < 4; j++) acc[i][j] = 0.0f;
    float r[8];
    #pragma unroll
    for (int m = 0; m < 8; m++) r[m] = rsh[PIDX(L0 + m)];
    #pragma unroll 4
    for (int k = 0; k < K_DIM; k += 4) {
        float dA[4][4];
        #pragma unroll
        for (int i = 0; i < 4; i++)
            *(float4*)dA[i] = *(const float4*)(duP + i * K_DIM + k);
        #pragma unroll
        for (int dk = 0; dk < 4; dk++) {
            #pragma unroll
            for (int i = 0; i < 4; i++) {
                float s = dA[i][dk];
                #pragma unroll
                for (int j = 0; j < 4; j++)
                    acc[i][j] = fmaf(s, r[j + dk], acc[i][j]);
            }
        }
        r[0] = r[4]; r[1] = r[5]; r[2] = r[6]; r[3] = r[7];
        #pragma unroll
        for (int m = 0; m < 4; m++) r[4 + m] = rsh[PIDX(L0 + k + 8 + m)];
    }
    float bv = -INFINITY;
    int bi = 0x7fffffff;
    #pragma unroll
    for (int i = 0; i < 4; i++) {
        int aa = a_lo + i;
        #pragma unroll
        for (int j = 0; j < 4; j++) {
            int fi = aa * T_DIM + t_lo + j;
            float v = acc[i][j];
            if (v > bv || (v == bv && fi < bi)) { bv = v; bi = fi; }
        }
    }
    #pragma unroll
    for (int off = 32; off > 0; off >>= 1) {
        float v2 = __shfl_down(bv, off);
        int   i2 = __shfl_down(bi, off);
        if (v2 > bv || (v2 == bv && i2 < bi)) { bv = v2; bi = i2; }
    }
    if ((tid & 63) == 0) red4[tid >> 6] = pack_vi(bv, bi);
    __syncthreads();
    if (tid == 0) {
        unsigned long long m = red4[0];
        #pragma unroll
        for (int w = 1; w < 4; w++) m = u64max(m, red4[w]);
        red4[0] = m;
    }
    __syncthreads();
    return red4[0];
}

// 8a x 256t engine (R13-proven bit-exact): 2 atoms/wave.
__device__ inline unsigned long long tile8(
    const float* __restrict__ duP, const float* __restrict__ rsh,
    int L0, int a_lo, int t_lo, int tid, unsigned long long* red4) {
    float acc[2][4];
    #pragma unroll
    for (int i = 0; i < 2; i++)
        #pragma unroll
        for (int j = 0; j < 4; j++) acc[i][j] = 0.0f;
    float r[8];
    #pragma unroll
    for (int m = 0; m < 8; m++) r[m] = rsh[PIDX(L0 + m)];
    #pragma unroll 4
    for (int k = 0; k < K_DIM; k += 4) {
        float dA[2][4];
        #pragma unroll
        for (int i = 0; i < 2; i++)
            *(float4*)dA[i] = *(const float4*)(duP + i * K_DIM + k);
        #pragma unroll
        for (int dk = 0; dk < 4; dk++) {
            #pragma unroll
            for (int i = 0; i < 2; i++) {
                float s = dA[i][dk];
                #pragma unroll
                for (int j = 0; j < 4; j++)
                    acc[i][j] = fmaf(s, r[j + dk], acc[i][j]);
            }
        }
        r[0] = r[4]; r[1] = r[5]; r[2] = r[6]; r[3] = r[7];
        #pragma unroll
        for (int m = 0; m < 4; m++) r[4 + m] = rsh[PIDX(L0 + k + 8 + m)];
    }
    float bv = -INFINITY;
    int bi = 0x7fffffff;
    #pragma unroll
    for (int i = 0; i < 2; i++) {
        int aa = a_lo + i;
        #pragma unroll
        for (int j = 0; j < 4; j++) {
            int fi = aa * T_DIM + t_lo + j;
            float v = acc[i][j];
            if (v > bv || (v == bv && fi < bi)) { bv = v; bi = fi; }
        }
    }
    #pragma unroll
    for (int off = 32; off > 0; off >>= 1) {
        float v2 = __shfl_down(bv, off);
        int   i2 = __shfl_down(bi, off);
        if (v2 > bv || (v2 == bv && i2 < bi)) { bv = v2; bi = i2; }
    }
    if ((tid & 63) == 0) red4[tid >> 6] = pack_vi(bv, bi);
    __syncthreads();
    if (tid == 0) {
        unsigned long long m = red4[0];
        #pragma unroll
        for (int w = 1; w < 4; w++) m = u64max(m, red4[w]);
        red4[0] = m;
    }
    __syncthreads();
    return red4[0];
}

// ---------------------------------------------------------------------------
// One fused kernel: step0 (2048 blocks) + persistent inc (260) + tail (1).
// R14: workers self-reduce the winner each step (poll 32 dsl slots directly,
// merge into a private LDS tile-table, reduce). This removes the coordinator
// round-trip (2 agent-scope hops/step -> 1) and the w0 handoff hop.
// Coordinator survives only as the lagging emb writer (off critical path).
__global__ __launch_bounds__(256) void k_mega(
    const float* __restrict__ a, const float* __restrict__ b,
    const float* __restrict__ du, const float* __restrict__ ae,
    const float* __restrict__ proj, float* __restrict__ emb,
    unsigned long long* __restrict__ arena, float* __restrict__ out) {

    __shared__ unsigned long long SMEM[SM_U64];
    unsigned long long* pmax = arena;
    unsigned long long* dsl  = arena + 2048;
    unsigned long long* w0   = arena + 33728;
    int*   cnt   = (int*)(arena + 33792);
    int*   done  = cnt + 128;
    float* norm2 = (float*)cnt + 160;

    int blk = blockIdx.x;
    int tid = threadIdx.x;

    if (blk < NB_STEP0) {
        // ===================== step0 role =====================
        int seq = blk >> 9;
        int idx = blk & 511;
        int a_base = (idx >> 6) * 16;
        int t0 = (idx & 63) * TT;
        float* rsh = (float*)SMEM;                       // PIDX<=394
        unsigned long long* pm_sh = SMEM + 256;
        unsigned long long* red4  = SMEM + 512;
        int* flag = (int*)(SMEM + 516);

        const float* x = (seq < 2 ? a : b) + (seq & 1) * T_DIM;
        for (int i = tid; i < SS_LEN; i += 256) {
            int t = t0 - 64 + i;
            rsh[PIDX(i)] = (t >= 0 && t < T_DIM) ? x[t] : 0.0f;
        }
        __syncthreads();
        int tg = tid & 63;
        int ag = __builtin_amdgcn_readfirstlane(tid >> 6);
        unsigned long long p = tile16(du + (a_base + ag * 4) * K_DIM, rsh,
                                      4 * tg, a_base + ag * 4, t0 + 4 * tg,
                                      tid, red4);
        if (tid == 0) {
            pmax[seq * NPT0 + idx] = p;
            __threadfence();
            flag[0] = (atomicAdd(&cnt[seq * 32], 1) == NPT0 - 1);
        }
        __syncthreads();
        if (!flag[0]) return;

        // last finisher: reduce for the step-0 embedding only (off critical
        // path now: workers self-reduce pmax after polling cnt).
        __threadfence();
        pm_sh[tid] = u64max(pmax[seq * NPT0 + tid], pmax[seq * NPT0 + 256 + tid]);
        __syncthreads();
        for (int off = 128; off > 0; off >>= 1) {
            if (tid < off) pm_sh[tid] = u64max(pm_sh[tid], pm_sh[tid + off]);
            __syncthreads();
        }
        float value; int fi;
        unpack_vi(pm_sh[0], &value, &fi);
        int ai = fi >> 14, ti = fi & (T_DIM - 1);
        int pos_idx = value > 0.0f ? ti : 0;
        int atom_idx = value > 0.0f ? ai : 0;
        float* e = emb + (seq * N_STEPS + 0) * 128;
        if (tid == 0) {
            e[0] = ((float)pos_idx / (float)(T_DIM - 1)) * 20.0f;
            e[1] = value;
        }
        if (tid >= 2 && tid < 2 + E_DIM) e[tid] = ae[atom_idx * E_DIM + tid - 2];
        __syncthreads();
        __threadfence();
        if (tid == 0) atomicExch(&w0[seq * SPAD], pm_sh[0]);   // legacy, unused
        return;
    }

    if (blk < NB_STEP0 + NB_INC) {
        int r = blk - NB_STEP0;
        int seq = r / 65;
        int sub = r - seq * 65;

        if (sub == 64) {
            // ============ coordinator: lagging emb writer only ============
            unsigned long long* table   = SMEM;          // 512
            unsigned long long* poll_sh = SMEM + 512;    // 32
            unsigned long long* red4    = SMEM + 548;

            if (tid == 0) pollcnt(&cnt[seq * 32], NPT0);
            __syncthreads();
            __threadfence();   // acquire: pmax writes ordered before cnt adds
            for (int i = tid; i < NPT0; i += 256) table[i] = pmax[seq * NPT0 + i];
            __syncthreads();
            {
                unsigned long long m0 = u64max(table[tid], table[tid + 256]);
                #pragma unroll
                for (int off = 32; off > 0; off >>= 1)
                    m0 = u64max(m0, __shfl_down(m0, off));
                if ((tid & 63) == 0) red4[tid >> 6] = m0;
            }
            __syncthreads();
            if (tid == 0) {
                unsigned long long w = red4[0];
                #pragma unroll
                for (int j = 1; j < 4; j++) w = u64max(w, red4[j]);
                red4[0] = w;
            }
            __syncthreads();
            float v0; int fi0;
            unpack_vi(red4[0], &v0, &fi0);
            int ti = fi0 & (T_DIM - 1);
            int lo = ti - 127; if (lo < 0) lo = 0;
            int hi = ti + 128; if (hi > T_DIM) hi = T_DIM;

            for (int step = 1; step < N_STEPS; step++) {
                int T0 = lo >> 8, T1 = T0 + 1;
                bool hasT1 = (T1 < NTT) && (T1 * TT < hi);
                if (tid < 32) {
                    if (((tid & 1) == 0) || hasT1)
                        poll_sh[tid] = pollu64(
                            &dsl[(((step - 1) * NSEQ + seq) * 32 + tid) * SPAD]);
                }
                __syncthreads();
                if (tid < 16) {
                    int at16 = tid >> 1, ts = tid & 1;
                    if (ts == 0 || hasT1)
                        table[at16 * 64 + (ts ? T1 : T0)] =
                            u64max(poll_sh[at16 * 4 + ts], poll_sh[at16 * 4 + 2 + ts]);
                }
                __syncthreads();
                unsigned long long m = u64max(table[tid], table[tid + 256]);
                #pragma unroll
                for (int off = 32; off > 0; off >>= 1)
                    m = u64max(m, __shfl_down(m, off));
                if ((tid & 63) == 0) red4[tid >> 6] = m;
                __syncthreads();
                if (tid == 0) {
                    unsigned long long w = red4[0];
                    #pragma unroll
                    for (int j = 1; j < 4; j++) w = u64max(w, red4[j]);
                    red4[0] = w;
                }
                __syncthreads();
                float value; int fi;
                unpack_vi(red4[0], &value, &fi);
                int wt = fi & (T_DIM - 1);
                int wa = fi >> 14;
                int pos_idx = value > 0.0f ? wt : 0;
                int atom_idx = value > 0.0f ? wa : 0;
                float* e = emb + (seq * N_STEPS + step) * 128;
                if (tid == 0) {
                    e[0] = ((float)pos_idx / (float)(T_DIM - 1)) * 20.0f;
                    e[1] = value;
                }
                if (tid >= 2 && tid < 128) e[tid] = ae[atom_idx * E_DIM + tid - 2];
                lo = wt - 127; if (lo < 0) lo = 0;
                hi = wt + 128; if (hi > T_DIM) hi = T_DIM;
            }
            __syncthreads();
            __threadfence();
            if (tid == 0) atomicAdd(done, 1);
            return;
        }

        // ===================== inc compute block =====================
        int atile = sub >> 2;                 // 0..15
        int half = (sub >> 1) & 1;
        int par = sub & 1;
        int a_base = atile * 8;
        int base = half * HB;
        float* resL = (float*)SMEM;                         // PIDX big (u64 < 4290)
        unsigned long long* red4   = SMEM + 4304;           // 4
        unsigned long long* pollsh = SMEM + 4320;           // 32 (overlaps snorm)
        unsigned long long* table  = SMEM + 4448;           // 512
        float* snorm = (float*)(SMEM + 4320);               // 256 f, post-loop only

        const float* x = (seq < 2 ? a : b) + (seq & 1) * T_DIM;
        for (int i = tid; i < RL_LEN; i += 256) {           // overlaps step0
            int t = base - 64 + i;
            resL[PIDX(i)] = (t >= 0 && t < T_DIM) ? x[t] : 0.0f;
        }
        if (tid == 0) pollcnt(&cnt[seq * 32], NPT0);
        __syncthreads();
        __threadfence();   // acquire: pmax writes ordered before cnt adds
        for (int i = tid; i < NPT0; i += 256) table[i] = pmax[seq * NPT0 + i];
        __syncthreads();
        {
            unsigned long long m0 = u64max(table[tid], table[tid + 256]);
            #pragma unroll
            for (int off = 32; off > 0; off >>= 1)
                m0 = u64max(m0, __shfl_down(m0, off));
            if ((tid & 63) == 0) red4[tid >> 6] = m0;
        }
        __syncthreads();
        if (tid == 0) {
            unsigned long long w = red4[0];
            #pragma unroll
            for (int j = 1; j < 4; j++) w = u64max(w, red4[j]);
            red4[0] = w;
        }
        __syncthreads();
        float v0; int fi0;
        unpack_vi(red4[0], &v0, &fi0);
        int ti0 = fi0 & (T_DIM - 1), ai0 = fi0 >> 14;
        if (tid < 128) {                                    // apply step-0
            int t = ti0 - 64 + tid;
            if (t >= 0 && t < T_DIM) {
                int L = t - base + 64;
                if (L >= 0 && L < RL_LEN) {
                    float rr = resL[PIDX(L)];
                    resL[PIDX(L)] = __fsub_rn(rr, __fmul_rn(v0, du[ai0 * K_DIM + tid]));
                }
            }
        }
        __syncthreads();
        int lo = ti0 - 127; if (lo < 0) lo = 0;
        int hi = ti0 + 128; if (hi > T_DIM) hi = T_DIM;

        for (int step = 1; step < N_STEPS; step++) {
            int T0 = lo >> 8, T1 = T0 + 1;
            bool hasT1 = (T1 < NTT) && (T1 * TT < hi);
            int cand = -1;
            if (((T0 & 1) == par) && ((T0 >> 5) == half)) cand = T0;
            else if (T1 < NTT && ((T1 & 1) == par) && ((T1 >> 5) == half) &&
                     T1 * TT < hi) cand = T1;

            if (cand >= 0) {
                int t0 = cand * TT;
                int tg = tid & 63;
                int ag = __builtin_amdgcn_readfirstlane(tid >> 6);
                unsigned long long p = tile8(
                    du + (a_base + ag * 2) * K_DIM, resL,
                    (t0 - base) + 4 * tg, a_base + ag * 2, t0 + 4 * tg, tid, red4);
                if (tid == 0)
                    atomicExch(&dsl[(((step - 1) * NSEQ + seq) * 32 +
                                     atile * 2 + (cand == T1 ? 1 : 0)) * SPAD], p);
            }
            // self-reduce the winner: poll all 32 slots, merge, reduce.
            if (tid < 32) {
                if (((tid & 1) == 0) || hasT1)
                    pollsh[tid] = pollu64(
                        &dsl[(((step - 1) * NSEQ + seq) * 32 + tid) * SPAD]);
            }
            __syncthreads();
            if (tid < 16) {
                int at16 = tid >> 1, ts = tid & 1;
                if (ts == 0 || hasT1)
                    table[at16 * 64 + (ts ? T1 : T0)] =
                        u64max(pollsh[at16 * 4 + ts], pollsh[at16 * 4 + 2 + ts]);
            }
            __syncthreads();
            unsigned long long m = u64max(table[tid], table[tid + 256]);
            #pragma unroll
            for (int off = 32; off > 0; off >>= 1)
                m = u64max(m, __shfl_down(m, off));
            if ((tid & 63) == 0) red4[tid >> 6] = m;
            __syncthreads();
            if (tid == 0) {
                unsigned long long w = red4[0];
                #pragma unroll
                for (int j = 1; j < 4; j++) w = u64max(w, red4[j]);
                red4[0] = w;
            }
            __syncthreads();
            float value; int fi;
            unpack_vi(red4[0], &value, &fi);
            int wt = fi & (T_DIM - 1);
            int wa = fi >> 14;
            if (tid < 128) {
                int t = wt - 64 + tid;
                if (t >= 0 && t < T_DIM) {
                    int L = t - base + 64;
                    if (L >= 0 && L < RL_LEN) {
                        float rr = resL[PIDX(L)];
                        resL[PIDX(L)] = __fsub_rn(rr, __fmul_rn(value, du[wa * K_DIM + tid]));
                    }
                }
            }
            __syncthreads();
            lo = wt - 127; if (lo < 0) lo = 0;
            hi = wt + 128; if (hi > T_DIM) hi = T_DIM;
        }

        if (atile == 0 && par == 0) {       // norm^2 partial for this half
            float s = 0.0f;
            for (int t = tid; t < HB; t += 256) {
                float v = resL[PIDX(t + 64)];
                s = fmaf(v, v, s);
            }
            snorm[tid] = s;
            __syncthreads();
            for (int off = 128; off > 0; off >>= 1) {
                if (tid < off) snorm[tid] += snorm[tid + off];
                __syncthreads();
            }
            if (tid == 0) {
                float old = atomicAdd(&norm2[seq * 32], snorm[0]);
                if (__float_as_uint(old) != 0xFFFFFFFFu)   // dep: order add after add
                    atomicAdd(done, 1);
            }
        }
        return;
    }

    // ===================== tail role =====================
    {
        float* keys  = (float*)SMEM;               // 64
        int*   order = (int*)(SMEM + 32);          // 64
        float* sh    = (float*)(SMEM + 64);        // 256
        float* norms = (float*)(SMEM + 192);       // 4

        if (tid == 0) {
            int c = __hip_atomic_load(done, __ATOMIC_RELAXED, __HIP_MEMORY_SCOPE_AGENT);
            while (c < 12) {
                __builtin_amdgcn_s_sleep(8);
                c = __hip_atomic_load(done, __ATOMIC_RELAXED, __HIP_MEMORY_SCOPE_AGENT);
            }
        }
        __syncthreads();
        __threadfence();   // acquire: emb + norm2 writes

        if (tid < NSEQ)
            norms[tid] = sqrtf(__hip_atomic_load(&norm2[tid * 32], __ATOMIC_RELAXED,
                                                 __HIP_MEMORY_SCOPE_AGENT));
        if (tid < 64) {
            int seq = tid >> 4, st = tid & 15;
            const float* e = emb + (seq * N_STEPS + st) * 128;
            float kk = 0.0f;
            for (int dd = 0; dd < 128; dd++) kk = fmaf(e[dd], proj[dd], kk);
            keys[tid] = kk;
        }
        __syncthreads();
        if (tid < NSEQ) {
            int ord[N_STEPS];
            for (int i = 0; i < N_STEPS; i++) ord[i] = i;
            for (int i = 1; i < N_STEPS; i++) {     // stable ascending
                int oi = ord[i];
                float kv = keys[tid * N_STEPS + oi];
                int j = i - 1;
                while (j >= 0 && keys[tid * N_STEPS + ord[j]] > kv) {
                    ord[j + 1] = ord[j]; j--;
                }
                ord[j + 1] = oi;
            }
            for (int i = 0; i < N_STEPS; i++) order[tid * N_STEPS + i] = ord[i];
        }
        __syncthreads();
        float s = 0.0f;
        #pragma unroll
        for (int t = 0; t < 16; t++) {
            int idx = tid + t * 256;
            int bq = idx >> 11;
            int st = (idx >> 7) & 15;
            int dd = idx & 127;
            float va = emb[((bq    ) * N_STEPS + order[bq * N_STEPS + st]) * 128 + dd];
            float vb = emb[((2 + bq) * N_STEPS + order[(2 + bq) * N_STEPS + st]) * 128 + dd];
            float df = va - vb;
            s = fmaf(df, df, s);
        }
        sh[tid] = s;
        __syncthreads();
        for (int off = 128; off > 0; off >>= 1) {
            if (tid < off) sh[tid] += sh[tid + off];
            __syncthreads();
        }
        if (tid == 0) {
            float mse = sh[0] / 4096.0f;
            float mad = 0.5f * (fabsf(norms[0] - norms[2]) + fabsf(norms[1] - norms[3]));
            out[0] = mse + mad;
        }
    }
}

// ---------------------------------------------------------------------------
extern "C" void kernel_launch(void* const* d_in, const int* in_sizes, int n_in,
                              void* d_out, int out_size, void* d_ws, size_t ws_size,
                              hipStream_t stream) {
    const float* a    = (const float*)d_in[0];
    const float* b    = (const float*)d_in[1];
    const float* d    = (const float*)d_in[2];
    const float* ae   = (const float*)d_in[3];
    const float* proj = (const float*)d_in[4];
    float* out = (float*)d_out;

    float* ws  = (float*)d_ws;
    float* du  = ws;                              // 16384 f
    float* emb = du + A_DIM * K_DIM;              // 8192 f
    unsigned long long* arena = (unsigned long long*)(emb + NSEQ * N_STEPS * 128);

    k_prep<<<192, 256, 0, stream>>>(d, du, arena);
    k_mega<<<NB_TOTAL, 256, 0, stream>>>(a, b, du, ae, proj, emb, arena, out);
}